// Round 1
// baseline (239.470 us; speedup 1.0000x reference)
//
#include <hip/hip_runtime.h>
#include <math.h>

#define H 2048
#define W 2048
#define K 16
#define SLW 292   // LDS row stride (floats): >=288 content cols, ==4 mod 32 banks

typedef float v4 __attribute__((ext_vector_type(4)));

// gather step for one k: 4 rows, 4 cols/lane, rotate-by-S dword select
template<int S>
__device__ __forceinline__ void gstep(const float* pk, v4* acc) {
#pragma unroll
  for (int rr = 0; rr < 4; ++rr) {
    v4 A = *(const v4*)(pk + rr * SLW);
    if constexpr (S == 0) {
      acc[rr] += A;
    } else {
      v4 B = *(const v4*)(pk + rr * SLW + 4);
      v4 r;
      if constexpr (S == 1)      r = (v4){A.y, A.z, A.w, B.x};
      else if constexpr (S == 2) r = (v4){A.z, A.w, B.x, B.y};
      else                       r = (v4){A.w, B.x, B.y, B.z};
      acc[rr] += r;
    }
  }
}

// Fully fused GENEO: per 32x256 output tile, compute the 48-row x 272-col win
// band in LDS (colsum vertical walk -> in-place horizontal 15-tap), then
// 16-tap gather from LDS. Virtual-index band [i0-8,i0+40) x [c0-8,c0+264);
// row wrap = two-segment vertical walk (by in {0,63}); col wrap = wrapped
// staging + masked horizontal groups (bx in {0,7}). Offsets outside [-8,8]
// (never for N(0,1) vectors) take the exact brute-force fallback.
__global__ __launch_bounds__(512, 4) void geneo_fused(
    const float* __restrict__ img,
    const float* __restrict__ patterns,
    const float* __restrict__ vectors,
    float* __restrict__ out) {
  __shared__ float sl[48][SLW];            // 56,064 B -> 2 blocks/CU
  __shared__ int   skoff[K], ssel[K], soy[K], sox[K];
  __shared__ float sred[8];
  __shared__ float sC;
  __shared__ int   sfit;

  const int t = threadIdx.x;
  // XCD-banded decode: xcd = d&7 owns 8 contiguous row-tiles (img band ~2.3MB -> L2)
  const int d  = blockIdx.x;
  const int by = ((d & 7) << 3) | ((d >> 3) >> 3);
  const int bx = (d >> 3) & 7;
  const int i0 = by << 5;
  const int c0 = bx << 8;

  // ---- phase 0: offsets, fit-check, pattern-sum constant ----
  int okbit = 1;
  if (t < K) {
    int oy = (int)floorf(vectors[2 * t]);
    int ox = (int)floorf(vectors[2 * t + 1]);
    int my = oy & (H - 1); if (my > 1024) my -= 2048;   // rep in [-1023,1024]
    int mx = ox & (W - 1); if (mx > 1024) mx -= 2048;
    soy[t] = my; sox[t] = mx;
    int bk = 24 - mx;                       // main-col base for this k
    skoff[t] = (8 - my) * SLW + (bk & ~3);  // slot-row offset + aligned col
    ssel[t]  = bk & 3;                      // rotate amount
    okbit = (my >= -8 && my <= 8 && mx >= -8 && mx <= 8);
  }
  if (t < 64) {
    unsigned long long bal = __ballot(okbit);
    if (t == 0) sfit = ((bal & 0xFFFFull) == 0xFFFFull) ? 1 : 0;
  }
  float ps;
  {
    const v4* p4 = (const v4*)patterns;     // 900 v4 = 3600 floats
    v4 a = p4[t];
    ps = (a.x + a.y) + (a.z + a.w);
    int t2 = t + 512;
    if (t2 < 900) { v4 b = p4[t2]; ps += (b.x + b.y) + (b.z + b.w); }
  }
#pragma unroll
  for (int q2 = 32; q2 > 0; q2 >>= 1) ps += __shfl_down(ps, q2, 64);
  if ((t & 63) == 0) sred[t >> 6] = ps;
  __syncthreads();                                   // B1
  if (t == 0) {
    float tot = ((sred[0] + sred[1]) + (sred[2] + sred[3]))
              + ((sred[4] + sred[5]) + (sred[6] + sred[7]));
    sC = (16.0f - tot * (1.0f / 225.0f)) * (1.0f / 15.0f);
  }

  if (!sfit) {
    // ---- exact fallback for arbitrary offsets (block-uniform; never taken
    // for the benchmark's N(0,1) vectors) ----
    __syncthreads();                                 // sC visibility
    const int L = t & 63, rb = (t >> 6) << 2;
    const float Sc = 1.0f / 3375.0f;
    const float Cc = sC;
    for (int rr = 0; rr < 4; ++rr) {
      for (int m = 0; m < 4; ++m) {
        const int i = i0 + rb + rr, j = c0 + 4 * L + m;
        float a = 0.f;
        for (int k = 0; k < K; ++k) {
          const int ri = (i - soy[k]) & (H - 1);
          const int rj = (j - sox[k]) & (W - 1);
          float wv = 0.f;
          for (int ay = 1; ay <= 15; ++ay) {
            const int r2 = ri - ay; if (r2 < 0) break;
            for (int ax = 1; ax <= 15; ++ax) {
              const int c2 = rj - ax; if (c2 < 0) break;
              wv += img[r2 * W + c2];
            }
          }
          a += wv;
        }
        out[i * W + j] = a * Sc + Cc;
      }
    }
    return;
  }

  // ---- phase A: vertical 15-row running sums, global -> LDS colsum ----
  // slot s (0..47) = colsum for virtual win row i0-8+s, main cols 0..287
  // (virtual img col c0-24+mc, content img[.&2047] -> wrapped staging).
  // by==0: fresh segment at step 8 (v=0); by==63: fresh at step 40 (v=2048);
  // fresh start == zero-pad semantics of the exclusive box window.
  if (t < 288) {
    const int q = t / 72, g = t - q * 72;        // 4 row-quarters x 72 v4-cols
    const int gcol = (c0 - 24 + 4 * g) & (W - 1);
    const float* ib = img + gcol;
    const int v0 = i0 - 8;
    const int RSTEP = (by == 0) ? 8 : ((by == 63) ? 40 : 1000);
    const int st0 = 12 * q;
    v4 s = (v4){0.f, 0.f, 0.f, 0.f};
    {
      const int vq = v0 + st0;
      const int segv = (st0 >= RSTEP) ? (v0 + RSTEP) : -100000;
#pragma unroll
      for (int a = 1; a <= 15; ++a) {            // warmup window, seg-clipped
        int u = vq - a;
        if (u >= segv) s += *(const v4*)&ib[(u & (H - 1)) * W];
      }
    }
#pragma unroll
    for (int stp = 0; stp < 12; ++stp) {
      const int step = st0 + stp;
      const int v = v0 + step;
      if (step == RSTEP) s = (v4){0.f, 0.f, 0.f, 0.f};
      *(v4*)&sl[step][4 * g] = s;                // colsum row v
      s += *(const v4*)&ib[(v & (H - 1)) * W];
      const int csg = (step >= RSTEP) ? RSTEP : -100000;
      if (step - 15 >= csg) s -= *(const v4*)&ib[((v - 15) & (H - 1)) * W];
    }
  }
  __syncthreads();                                   // B2

  // ---- phase B: horizontal 15-tap, in-place (win at main cols 16..287) ----
  // 96 threads: 48 rows x 2 halves of 34 groups; reg-carry sweep makes the
  // in-place overwrite safe (writes land +16 cols behind the read window).
  v4 W0, W1, W2, W3, W4;
  int pr = 0, ph = 0;
  if (t < 96) {
    ph = (t >= 48); pr = t - 48 * ph;
    const int cb = 136 * ph;
    W0 = *(const v4*)&sl[pr][cb +  0];
    W1 = *(const v4*)&sl[pr][cb +  4];
    W2 = *(const v4*)&sl[pr][cb +  8];
    W3 = *(const v4*)&sl[pr][cb + 12];
    W4 = *(const v4*)&sl[pr][cb + 16];
  }
  __syncthreads();                                   // B3 (inits vs writes)
  if (t < 96) {
    const int thr = (bx == 0) ? 24 : 280;  // main-col zero-pad threshold
    for (int gg = 0; gg < 34; ++gg) {
      const int gp = 34 * ph + gg;
      v4 M0 = W0, M1 = W1, M2 = W2, M3 = W3;
      const bool needmask = (bx == 0) ? (gp >= 2 && gp <= 5)
                          : ((bx == 7) ? (gp >= 66) : false);
      if (needmask) {                       // zero cols left of the junction
        const int mb = thr - 4 * gp;        // element idx < mb -> 0 (mb<=16)
        if ( 0 < mb) M0.x = 0.f; if ( 1 < mb) M0.y = 0.f;
        if ( 2 < mb) M0.z = 0.f; if ( 3 < mb) M0.w = 0.f;
        if ( 4 < mb) M1.x = 0.f; if ( 5 < mb) M1.y = 0.f;
        if ( 6 < mb) M1.z = 0.f; if ( 7 < mb) M1.w = 0.f;
        if ( 8 < mb) M2.x = 0.f; if ( 9 < mb) M2.y = 0.f;
        if (10 < mb) M2.z = 0.f; if (11 < mb) M2.w = 0.f;
        if (12 < mb) M3.x = 0.f; if (13 < mb) M3.y = 0.f;
        if (14 < mb) M3.z = 0.f; if (15 < mb) M3.w = 0.f;
      }
      float s0 = ((M0.y + M0.z) + (M0.w + M1.x))
               + ((M1.y + M1.z) + (M1.w + M2.x))
               + ((M2.y + M2.z) + (M2.w + M3.x))
               + ((M3.y + M3.z) + M3.w);
      float s1 = s0 - M0.y + W4.x;
      float s2 = s1 - M0.z + W4.y;
      float s3 = s2 - M0.w + W4.z;
      *(v4*)&sl[pr][16 + 4 * gp] = (v4){s0, s1, s2, s3};
      W0 = W1; W1 = W2; W2 = W3; W3 = W4;
      if (gg < 33) W4 = *(const v4*)&sl[pr][4 * gp + 20];
    }
  }
  __syncthreads();                                   // B4

  // ---- phase C: 16-tap gather from LDS + epilogue ----
  // whole wave reads ONE win row per (k,rr) at 16B/lane: conflict-free b128.
  const int L = t & 63, rb = (t >> 6) << 2;          // 8 warps x 4 rows
  const float* lp = &sl[0][0];
  const int tb = 4 * L + rb * SLW;
  v4 acc[4];
#pragma unroll
  for (int rr = 0; rr < 4; ++rr) acc[rr] = (v4){0.f, 0.f, 0.f, 0.f};
#pragma unroll
  for (int k = 0; k < K; ++k) {
    const float* pk = lp + skoff[k] + tb;
    const int sf = __builtin_amdgcn_readfirstlane(ssel[k]);
    switch (sf) {
      case 0:  gstep<0>(pk, acc); break;
      case 1:  gstep<1>(pk, acc); break;
      case 2:  gstep<2>(pk, acc); break;
      default: gstep<3>(pk, acc); break;
    }
  }
  const float Cc = sC;
#pragma unroll
  for (int rr = 0; rr < 4; ++rr) {
    v4 o = acc[rr] * (1.0f / 3375.0f) + Cc;
    __builtin_nontemporal_store(o, (v4*)&out[(i0 + rb + rr) * W + c0 + 4 * L]);
  }
}

extern "C" void kernel_launch(void* const* d_in, const int* in_sizes, int n_in,
                              void* d_out, int out_size, void* d_ws, size_t ws_size,
                              hipStream_t stream) {
  const float* x        = (const float*)d_in[0];  // (1,1,H,W)
  const float* patterns = (const float*)d_in[1];  // (K,P,P)
  const float* vectors  = (const float*)d_in[2];  // (K,2)
  // single fused launch; workspace unused
  geneo_fused<<<512, 512, 0, stream>>>(x, patterns, vectors, (float*)d_out);
}

// Round 2
// 93.417 us; speedup vs baseline: 2.5635x; 2.5635x over previous
//
#include <hip/hip_runtime.h>
#include <math.h>

#define H 2048
#define W 2048
#define K 16
#define P 15
#define WP 2052        // win pitch: W + 4 replicated guard cols
#define LDSP 272       // k1 LDS pitch: 256 tile cols + 16 halo cols
#define SLP 148        // k2 LDS pitch: 144 content cols + 4 pad

typedef float v4 __attribute__((ext_vector_type(4)));

// ---- kernel 1: fused 15x15 exclusive box-sum img -> win, LDS-staged ----
// VERBATIM from the 89 us baseline. Block = 32x256 tile, 320 threads, 52 KB.
// NOTE (R7/R9/R12): do NOT sort/dedup the offsets.
__global__ __launch_bounds__(320) void geneo_win(
        const float* __restrict__ img,
        float* __restrict__ win,
        const float* __restrict__ patterns,
        const float* __restrict__ vectors,
        float* __restrict__ consts,
        int* __restrict__ offs) {
    __shared__ float sl[48][LDSP];   // 52,224 B
    __shared__ float psum[5];
    int t  = threadIdx.x;
    int c0 = blockIdx.x * 256;
    int r0 = blockIdx.y * 32;

    if (blockIdx.x == 0 && blockIdx.y == 0) {
        float ps = 0.f;
        for (int idx = t; idx < 900; idx += 320) {
            v4 v = *(const v4*)&patterns[idx * 4];
            ps += (v.x + v.y) + (v.z + v.w);
        }
        #pragma unroll
        for (int q = 32; q > 0; q >>= 1) ps += __shfl_down(ps, q, 64);
        if ((t & 63) == 0) psum[t >> 6] = ps;
        if (t < 2 * K) offs[t] = (int)floorf(vectors[t]);
        __syncthreads();
        if (t == 0) {
            float total = ((psum[0] + psum[1]) + (psum[2] + psum[3])) + psum[4];
            consts[0] = (16.0f - total * (1.0f / 225.0f)) * (1.0f / 15.0f);
        }
    }

    for (int idx = t; idx < 47 * 68; idx += 320) {
        int q = idx / 68;
        int c = idx - q * 68;
        int grow = r0 - 15 + q;
        int gcol = c0 - 16 + 4 * c;
        v4 v = {0.f, 0.f, 0.f, 0.f};
        if (grow >= 0 && gcol >= 0)
            v = *(const v4*)&img[grow * W + gcol];
        *(v4*)&sl[q + 1][4 * c] = v;
    }
    __syncthreads();

    if (t < LDSP) {
        float s = 0.f;
        #pragma unroll
        for (int q = 1; q <= 15; ++q) s += sl[q][t];
        #pragma unroll
        for (int ii = 0; ii < 32; ++ii) {
            float sv = s;
            s += sl[ii + 16][t] - sl[ii + 1][t];
            sl[ii][t] = sv;
        }
    }
    __syncthreads();

    if (t < 256) {
        int g  = t & 63;
        int rb = (t >> 6) * 8;
        #pragma unroll
        for (int rr = 0; rr < 8; ++rr) {
            int ii = rb + rr;
            const float* row = &sl[ii][4 * g];
            v4 V0 = *(const v4*)&row[0];
            v4 V1 = *(const v4*)&row[4];
            v4 V2 = *(const v4*)&row[8];
            v4 V3 = *(const v4*)&row[12];
            v4 V4 = *(const v4*)&row[16];
            float s0 = ((V0.y + V0.z) + (V0.w + V1.x))
                     + ((V1.y + V1.z) + (V1.w + V2.x))
                     + ((V2.y + V2.z) + (V2.w + V3.x))
                     + ((V3.y + V3.z) + V3.w);
            float s1 = s0 - V0.y + V4.x;
            float s2 = s1 - V0.z + V4.y;
            float s3 = s2 - V0.w + V4.z;
            v4 r4 = {s0, s1, s2, s3};
            int gi = r0 + ii;
            *(v4*)&win[gi * WP + c0 + 4 * g] = r4;
            if (c0 == 0 && g == 0)
                *(v4*)&win[gi * WP + 2048] = r4;
        }
    }
}

// gather step for one k: two rows/thread, rotate-by-S dword select
template<int S>
__device__ __forceinline__ void gstep2(const float* pk, int ro0, int ro1,
                                       v4& a0, v4& a1) {
    v4 A0 = *(const v4*)(pk + ro0);
    v4 A1 = *(const v4*)(pk + ro1);
    if constexpr (S == 0) {
        a0 += A0; a1 += A1;
    } else {
        v4 B0 = *(const v4*)(pk + ro0 + 4);
        v4 B1 = *(const v4*)(pk + ro1 + 4);
        v4 r0, r1;
        if constexpr (S == 1)      { r0 = (v4){A0.y, A0.z, A0.w, B0.x};
                                     r1 = (v4){A1.y, A1.z, A1.w, B1.x}; }
        else if constexpr (S == 2) { r0 = (v4){A0.z, A0.w, B0.x, B0.y};
                                     r1 = (v4){A1.z, A1.w, B1.x, B1.y}; }
        else                       { r0 = (v4){A0.w, B0.x, B0.y, B0.z};
                                     r1 = (v4){A1.w, B1.x, B1.y, B1.z}; }
        a0 += r0; a1 += r1;
    }
}

// ---- kernel 2: LDS-staged 16-way circular-shift gather-sum ----
// Tile = 16 rows x 128 cols. Stage the 32x144 win band once (aligned v4,
// circular row/col wrap), gather 16 taps from LDS: each half-wave reads ONE
// win row at 16B/lane -> conflict-free ds_read_b128, aligned + reg rotate.
// 19 KB LDS, 256 thr -> 8 blocks/CU = 32 waves/CU. XCD-banded rows: xcd
// d&7 owns win rows [xcd*256-8, (xcd+1)*256+8) ~ 2.1 MB -> per-XCD L2.
// Offsets outside [-8,8] (never for N(0,1) vectors): exact direct-global
// fallback against win.
__global__ __launch_bounds__(256) void geneo_gather2(
        const float* __restrict__ win,
        const float* __restrict__ consts,
        const int* __restrict__ offs,
        float* __restrict__ out) {
    __shared__ float sl[32][SLP];            // 18,944 B
    __shared__ int   skoff[K], ssel[K], soy[K], sox[K];
    __shared__ float sC;
    __shared__ int   sfit;

    const int t = threadIdx.x;
    const int d = blockIdx.x;                // 2048 blocks
    const int q = d >> 3;
    const int by = ((d & 7) << 4) | (q >> 4);   // [0,128) row-tile
    const int bx = q & 15;                      // [0,16)  col-tile
    const int i0 = by << 4;
    const int c0 = bx << 7;

    // ---- phase 0: offsets + constant ----
    int okbit = 1;
    if (t < K) {
        int oy = offs[2 * t], ox = offs[2 * t + 1];
        int my = oy & (H - 1); if (my > 1024) my -= 2048;
        int mx = ox & (W - 1); if (mx > 1024) mx -= 2048;
        soy[t] = oy; sox[t] = ox;
        int bk = 8 - mx;                       // in [0,16] when fit
        skoff[t] = (8 - my) * SLP + (bk & ~3);
        ssel[t]  = bk & 3;
        okbit = (my >= -8 && my <= 8 && mx >= -8 && mx <= 8);
    }
    if (t < 64) {
        unsigned long long bal = __ballot(okbit);
        if (t == 0) sfit = ((bal & 0xFFFFull) == 0xFFFFull) ? 1 : 0;
    }
    if (t == 0) sC = consts[0];

    // ---- stage win band rows [i0-8,i0+24) x cols [c0-8,c0+136) ----
    // circular wrap; all v4-aligned (c0-8 multiple of 4, & keeps alignment)
    for (int idx = t; idx < 32 * 36; idx += 256) {
        int r = idx / 36;
        int g = idx - r * 36;
        int grow = (i0 - 8 + r) & (H - 1);
        int gcol = (c0 - 8 + 4 * g) & (W - 1);
        *(v4*)&sl[r][4 * g] = *(const v4*)&win[grow * WP + gcol];
    }
    __syncthreads();

    const float S = 1.0f / 3375.0f;
    const float Cc = sC;
    const int cg = t & 31;                   // v4 col group [0,32)
    const int r0 = t >> 5;                   // rows r0 and r0+8
    const int ro0 = r0 * SLP;
    const int ro1 = (r0 + 8) * SLP;

    if (!sfit) {
        // exact direct-global fallback (block-uniform; never taken here)
        for (int e = 0; e < 4; ++e) {
            const int j = c0 + 4 * cg + e;
            float a0 = 0.f, a1 = 0.f;
            for (int k = 0; k < K; ++k) {
                const int rj = (j - sox[k]) & (W - 1);
                a0 += win[(((i0 + r0    ) - soy[k]) & (H - 1)) * WP + rj];
                a1 += win[(((i0 + r0 + 8) - soy[k]) & (H - 1)) * WP + rj];
            }
            out[(i0 + r0    ) * W + j] = a0 * S + Cc;
            out[(i0 + r0 + 8) * W + j] = a1 * S + Cc;
        }
        return;
    }

    // ---- 16-tap gather from LDS ----
    const float* lp = &sl[0][0];
    const int tb = 4 * cg;
    v4 acc0 = {0.f, 0.f, 0.f, 0.f};
    v4 acc1 = {0.f, 0.f, 0.f, 0.f};
    #pragma unroll
    for (int k = 0; k < K; ++k) {
        const float* pk = lp + skoff[k] + tb;
        const int sf = __builtin_amdgcn_readfirstlane(ssel[k]);
        switch (sf) {
            case 0:  gstep2<0>(pk, ro0, ro1, acc0, acc1); break;
            case 1:  gstep2<1>(pk, ro0, ro1, acc0, acc1); break;
            case 2:  gstep2<2>(pk, ro0, ro1, acc0, acc1); break;
            default: gstep2<3>(pk, ro0, ro1, acc0, acc1); break;
        }
    }
    v4 o0 = acc0 * S + Cc;
    v4 o1 = acc1 * S + Cc;
    __builtin_nontemporal_store(o0, (v4*)&out[(i0 + r0    ) * W + c0 + 4 * cg]);
    __builtin_nontemporal_store(o1, (v4*)&out[(i0 + r0 + 8) * W + c0 + 4 * cg]);
}

extern "C" void kernel_launch(void* const* d_in, const int* in_sizes, int n_in,
                              void* d_out, int out_size, void* d_ws, size_t ws_size,
                              hipStream_t stream) {
    const float* x        = (const float*)d_in[0]; // (1,1,H,W)
    const float* patterns = (const float*)d_in[1]; // (K,P,P)
    const float* vectors  = (const float*)d_in[2]; // (K,2)
    float* out = (float*)d_out;

    float* win    = (float*)d_ws;          // H*WP floats
    float* consts = win + H * WP;          // 1 float
    int*   offs   = (int*)(consts + 1);    // 2K ints (oy,ox pairs)

    geneo_win<<<dim3(8, 64), 320, 0, stream>>>(x, win, patterns, vectors, consts, offs);
    geneo_gather2<<<2048, 256, 0, stream>>>(win, consts, offs, out);
}

// Round 3
// 89.677 us; speedup vs baseline: 2.6704x; 1.0417x over previous
//
#include <hip/hip_runtime.h>
#include <math.h>

#define H 2048
#define W 2048
#define K 16
#define P 15
#define WP 2052        // win pitch: W + 4 replicated guard cols (wrapped float4 reads)
#define LDSP 272       // LDS pitch: 256 tile cols + 16 halo cols

typedef float v4 __attribute__((ext_vector_type(4)));
typedef v4 uv4 __attribute__((aligned(4)));   // dword-aligned vector load

// ---- kernel 1: fused 15x15 exclusive box-sum img -> win, LDS-staged ----
// Block = 32-row x 256-col tile, 320 threads, 52 KB LDS.
// R3: 1D grid with ROW-banded XCD decode — XCD x computes win rows
// [256x, 256x+256), matching kernel 2's row-banded reads, so k2's win
// reads hit the LOCAL per-XCD L2 instead of snooping another XCD's
// dirty lines through L3. (Was dim3(8,64): column-banded, 100% cross-XCD.)
// NOTE (R7/R9/R12): do NOT sort/dedup the offsets — unsorted order is ~11 us
// faster (sorted k-runs hotspot the same win row grid-wide).
__global__ __launch_bounds__(320) void geneo_win(
        const float* __restrict__ img,
        float* __restrict__ win,
        const float* __restrict__ patterns,
        const float* __restrict__ vectors,
        float* __restrict__ consts,
        int* __restrict__ offs) {
    // slot s (s=1..47) holds img row r0-16+s; the vertical walk overwrites
    // slot ii with colsum row r0+ii (slot ii's img row is dead by then).
    __shared__ float sl[48][LDSP];   // 52,224 B
    __shared__ float psum[5];
    int t  = threadIdx.x;
    // XCD-row-banded decode: xcd = d&7 owns row-tiles [8*xcd, 8*xcd+8)
    int d  = blockIdx.x;             // 512 blocks
    int by = ((d & 7) << 3) | ((d >> 3) & 7);
    int bx = d >> 6;
    int c0 = bx * 256;
    int r0 = by * 32;

    // --- consts (block d==0 only: by=0, bx=0) ---
    if (d == 0) {
        float ps = 0.f;
        for (int idx = t; idx < 900; idx += 320) {      // 900 v4 = 3600 floats
            v4 v = *(const v4*)&patterns[idx * 4];
            ps += (v.x + v.y) + (v.z + v.w);
        }
        #pragma unroll
        for (int q = 32; q > 0; q >>= 1) ps += __shfl_down(ps, q, 64);
        if ((t & 63) == 0) psum[t >> 6] = ps;
        if (t < 2 * K) offs[t] = (int)floorf(vectors[t]);
        __syncthreads();
        if (t == 0) {
            float total = ((psum[0] + psum[1]) + (psum[2] + psum[3])) + psum[4];
            consts[0] = (16.0f - total * (1.0f / 225.0f)) * (1.0f / 15.0f);
        }
    }

    // --- stage img rows [r0-15, r0+32) x cols [c0-16, c0+256) into LDS ---
    for (int idx = t; idx < 47 * 68; idx += 320) {
        int q = idx / 68;                 // 0..46 -> img row r0-15+q -> slot q+1
        int c = idx - q * 68;             // v4 col group
        int grow = r0 - 15 + q;
        int gcol = c0 - 16 + 4 * c;
        v4 v = {0.f, 0.f, 0.f, 0.f};
        if (grow >= 0 && gcol >= 0)       // zero-pad (gcol<0 => whole v4 < 0)
            v = *(const v4*)&img[grow * W + gcol];
        *(v4*)&sl[q + 1][4 * c] = v;
    }
    __syncthreads();

    // --- vertical running sum in LDS (one column/thread, stride-1 lanes) ---
    if (t < LDSP) {
        float s = 0.f;
        #pragma unroll
        for (int q = 1; q <= 15; ++q) s += sl[q][t];     // rows r0-15..r0-1
        #pragma unroll
        for (int ii = 0; ii < 32; ++ii) {
            float sv = s;
            s += sl[ii + 16][t] - sl[ii + 1][t];         // +row r0+ii, -row r0+ii-15
            sl[ii][t] = sv;                              // colsum row r0+ii
        }
    }
    __syncthreads();

    // --- phase B: horizontal 15-tap, 4 cols/thread via 5 aligned ds_read_b128 ---
    // output cols c0+4g..c0+4g+3 need lds cols 4g+1..4g+18 (subset of [4g,4g+20))
    if (t < 256) {
        int g  = t & 63;                  // col group
        int rb = (t >> 6) * 8;            // 8 rows per thread
        #pragma unroll
        for (int rr = 0; rr < 8; ++rr) {
            int ii = rb + rr;
            const float* row = &sl[ii][4 * g];
            v4 V0 = *(const v4*)&row[0];
            v4 V1 = *(const v4*)&row[4];
            v4 V2 = *(const v4*)&row[8];
            v4 V3 = *(const v4*)&row[12];
            v4 V4 = *(const v4*)&row[16];
            float s0 = ((V0.y + V0.z) + (V0.w + V1.x))
                     + ((V1.y + V1.z) + (V1.w + V2.x))
                     + ((V2.y + V2.z) + (V2.w + V3.x))
                     + ((V3.y + V3.z) + V3.w);
            float s1 = s0 - V0.y + V4.x;
            float s2 = s1 - V0.z + V4.y;
            float s3 = s2 - V0.w + V4.z;
            v4 r4 = {s0, s1, s2, s3};
            int gi = r0 + ii;
            *(v4*)&win[gi * WP + c0 + 4 * g] = r4;
            if (c0 == 0 && g == 0)        // guard cols 2048..2051 = cols 0..3
                *(v4*)&win[gi * WP + 2048] = r4;
        }
    }
}

// ---- kernel 2: 16-way circular-shift gather-sum, XCD-banded, 8 out/thread ----
// VERBATIM from the 89 us baseline (R2 showed LDS staging is +4 us here).
// out stores are nontemporal (nt): out lines are never re-read, and without
// the hint they compete with the ~2.1 MB win band for the 4 MiB per-XCD L2.
__global__ __launch_bounds__(256) void geneo_gather(
        const float* __restrict__ win,
        const float* __restrict__ consts,
        const int* __restrict__ offs,
        float* __restrict__ out) {
    __shared__ int soy[K], sox[K];
    __shared__ float sC;
    int t = threadIdx.x;
    if (t < K) { soy[t] = offs[t * 2]; sox[t] = offs[t * 2 + 1]; }
    if (t == 0) sC = consts[0];
    __syncthreads();

    // round-robin d%8 XCD assignment: XCD x gets rows [x*256, x*256+256)
    // -> its win band (~2.1 MB) fits the 4 MiB per-XCD L2 (and is now
    // written there by kernel 1's matching row-banded decode)
    int d = blockIdx.x;              // 2048 blocks, one output row each
    int i = ((d & 7) << 8) | (d >> 3);
    int j = 4 * t;                   // cols j and j+1024 per thread

    const float S = 1.0f / 3375.0f;  // 1/(p^2 (K-1)), data-independent
    v4 acc0 = {0.f, 0.f, 0.f, 0.f};
    v4 acc1 = {0.f, 0.f, 0.f, 0.f};
    #pragma unroll
    for (int k = 0; k < K; ++k) {    // MUST stay compile-time unrolled (R9 lesson)
        int ri = (i - soy[k]) & (H - 1);
        int rj = (j - sox[k]) & (W - 1);
        const float* row = &win[ri * WP];
        acc0 += *(const uv4*)&row[rj];
        acc1 += *(const uv4*)&row[rj ^ 1024];   // (rj+1024) mod 2048
    }
    v4 o0 = acc0 * S + sC;
    v4 o1 = acc1 * S + sC;
    __builtin_nontemporal_store(o0, (v4*)&out[i * W + j]);
    __builtin_nontemporal_store(o1, (v4*)&out[i * W + j + 1024]);
}

extern "C" void kernel_launch(void* const* d_in, const int* in_sizes, int n_in,
                              void* d_out, int out_size, void* d_ws, size_t ws_size,
                              hipStream_t stream) {
    const float* x        = (const float*)d_in[0]; // (1,1,H,W)
    const float* patterns = (const float*)d_in[1]; // (K,P,P)
    const float* vectors  = (const float*)d_in[2]; // (K,2)
    float* out = (float*)d_out;

    float* win    = (float*)d_ws;          // H*WP floats
    float* consts = win + H * WP;          // 1 float
    int*   offs   = (int*)(consts + 1);    // 2K ints (oy,ox pairs)

    geneo_win<<<512, 320, 0, stream>>>(x, win, patterns, vectors, consts, offs);
    geneo_gather<<<2048, 256, 0, stream>>>(win, consts, offs, out);
}